// Round 2
// baseline (376.203 us; speedup 1.0000x reference)
//
#include <hip/hip_runtime.h>

// Problem constants
#define BS1 32
#define BS2 128
#define NEC 64
#define QD  256   // Q_DIM
#define MD  256   // MLP_DIM (== MEM_DIM)

typedef float fx4 __attribute__((ext_vector_type(4)));   // nontemporal-store-compatible

// Fused prep kernel, 256 threads/block:
//   blocks [0,256):   proj_c rows 8*blk      = crit rows @ W_mlp[:256,:]
//   blocks [256,272): proj_e rows 8*(blk-256) = ehr rows @ W_mlp[256:,:]
//   blocks [272,304): att[b,:] = softmax_e(crit[b,e,:] . W_align[:256]), b = blk-272
//                     (logit_e[p] and b_align are constant over axis e -> cancel)
__global__ __launch_bounds__(256)
void prep_kernel(const float* __restrict__ crit,
                 const float* __restrict__ ehr,
                 const float* __restrict__ w_mlp,
                 const float* __restrict__ w_align,
                 float* __restrict__ proj_c,
                 float* __restrict__ proj_e,
                 float* __restrict__ att) {
    __shared__ float smem[8 * QD];     // GEMM A-tile (8 KB) or wa[256]
    __shared__ float logits[NEC];
    int tid = threadIdx.x;
    int blk = blockIdx.x;

    if (blk < 272) {
        // ---- 8-row GEMM: out[m0:m0+8, :] = A[m0:m0+8, :] @ B ----
        const float* A; const float* B; float* out; int m0;
        if (blk < 256) { A = crit; B = w_mlp;           out = proj_c; m0 = blk * 8; }
        else           { A = ehr;  B = w_mlp + QD * MD; out = proj_e; m0 = (blk - 256) * 8; }
        {
            const float* src = A + m0 * QD + tid * 8;
            float4 a0 = *(const float4*)src;
            float4 a1 = *(const float4*)(src + 4);
            *(float4*)&smem[tid * 8]     = a0;
            *(float4*)&smem[tid * 8 + 4] = a1;
        }
        __syncthreads();
        int r = tid >> 5;            // row in [0,8)
        int c = (tid & 31) * 8;      // col base
        float acc[8] = {0.f,0.f,0.f,0.f,0.f,0.f,0.f,0.f};
        #pragma unroll 4
        for (int k = 0; k < QD; ++k) {
            float a = smem[r * QD + k];
            const float* bp = B + k * MD + c;
            float4 b0 = *(const float4*)bp;
            float4 b1 = *(const float4*)(bp + 4);
            acc[0] = fmaf(a, b0.x, acc[0]);
            acc[1] = fmaf(a, b0.y, acc[1]);
            acc[2] = fmaf(a, b0.z, acc[2]);
            acc[3] = fmaf(a, b0.w, acc[3]);
            acc[4] = fmaf(a, b1.x, acc[4]);
            acc[5] = fmaf(a, b1.y, acc[5]);
            acc[6] = fmaf(a, b1.z, acc[6]);
            acc[7] = fmaf(a, b1.w, acc[7]);
        }
        float* o = out + (m0 + r) * MD + c;
        *(float4*)o       = make_float4(acc[0], acc[1], acc[2], acc[3]);
        *(float4*)(o + 4) = make_float4(acc[4], acc[5], acc[6], acc[7]);
    } else {
        // ---- att for one b: 4 lanes per e-row ----
        int b = blk - 272;
        smem[tid] = w_align[tid];            // wa[0:256]
        __syncthreads();
        int e = tid >> 2, q = tid & 3;
        const float* row = crit + (b * NEC + e) * QD + q * 64;
        const float* w   = &smem[q * 64];
        float acc = 0.f;
        #pragma unroll
        for (int k = 0; k < 64; k += 4) {
            float4 u = *(const float4*)(row + k);
            acc = fmaf(u.x, w[k + 0], acc);
            acc = fmaf(u.y, w[k + 1], acc);
            acc = fmaf(u.z, w[k + 2], acc);
            acc = fmaf(u.w, w[k + 3], acc);
        }
        // sum the 4-lane group (lanes q^1, q^2 within the wave)
        acc += __shfl_xor(acc, 1);
        acc += __shfl_xor(acc, 2);
        if (q == 0) logits[e] = acc;
        __syncthreads();
        if (tid < NEC) {                     // wave 0 does the 64-wide softmax
            float l = logits[tid];
            float m = l;
            #pragma unroll
            for (int off = 32; off; off >>= 1) m = fmaxf(m, __shfl_xor(m, off));
            float ex = __expf(l - m);
            float s = ex;
            #pragma unroll
            for (int off = 32; off; off >>= 1) s += __shfl_xor(s, off);
            att[b * NEC + tid] = ex / s;
        }
    }
}

// h[b,p,e,d] = att[b,e] * (proj_c[b,e,d] + proj_e[p,d]) + b_mlp[d]
// One block per (b,p). LDS-free: pe/bm/att are loop-invariant per thread,
// held in registers; proj_c read from L2; output streamed with NT stores.
__global__ __launch_bounds__(256)
void final_kernel(const float* __restrict__ att,
                  const float* __restrict__ proj_c,
                  const float* __restrict__ proj_e,
                  const float* __restrict__ b_mlp,
                  float*       __restrict__ out) {
    int tid = threadIdx.x;
    int bp  = blockIdx.x;
    int b = bp >> 7, p = bp & 127;
    int wid = tid >> 5;                 // [0,8)
    int d   = (tid & 31) * 8;           // [0,256) step 8

    const float4 e0 = *(const float4*)(proj_e + p * MD + d);
    const float4 e1 = *(const float4*)(proj_e + p * MD + d + 4);
    const float4 m0 = *(const float4*)(b_mlp + d);
    const float4 m1 = *(const float4*)(b_mlp + d + 4);

    const float* attp = att + b * NEC + wid;
    float a[8];
    #pragma unroll
    for (int pass = 0; pass < 8; ++pass) a[pass] = attp[pass * 8];

    // e = pass*8 + wid; idx = pass*256 + tid; out offset = idx*8 (wave-contiguous 2 KiB)
    const float* pc = proj_c + (b * NEC + wid) * MD + d;
    float*       o  = out + (size_t)bp * (NEC * MD) + tid * 8;

    #pragma unroll
    for (int pass = 0; pass < 8; ++pass) {
        float4 c0 = *(const float4*)pc;
        float4 c1 = *(const float4*)(pc + 4);
        fx4 r0, r1;
        r0.x = fmaf(a[pass], c0.x + e0.x, m0.x);
        r0.y = fmaf(a[pass], c0.y + e0.y, m0.y);
        r0.z = fmaf(a[pass], c0.z + e0.z, m0.z);
        r0.w = fmaf(a[pass], c0.w + e0.w, m0.w);
        r1.x = fmaf(a[pass], c1.x + e1.x, m1.x);
        r1.y = fmaf(a[pass], c1.y + e1.y, m1.y);
        r1.z = fmaf(a[pass], c1.z + e1.z, m1.z);
        r1.w = fmaf(a[pass], c1.w + e1.w, m1.w);
        __builtin_nontemporal_store(r0, (fx4*)o);
        __builtin_nontemporal_store(r1, (fx4*)(o + 4));
        pc += 8 * MD;      // e advances by 8 per pass
        o  += 256 * 8;     // idx advances by 256 threads * 8 floats
    }
}

extern "C" void kernel_launch(void* const* d_in, const int* in_sizes, int n_in,
                              void* d_out, int out_size, void* d_ws, size_t ws_size,
                              hipStream_t stream) {
    // setup_inputs order: ehr_vector, criteria, ec_mask, W_align, b_align, W_mlp, b_mlp
    const float* ehr     = (const float*)d_in[0];   // (128, 256) fp32
    const float* crit    = (const float*)d_in[1];   // (32, 64, 256) fp32
    // d_in[2] ec_mask: all-ones, unused by reference
    const float* w_align = (const float*)d_in[3];   // (512,) -> use [:256]
    // d_in[4] b_align: cancels in softmax
    const float* w_mlp   = (const float*)d_in[5];   // (512, 256) row-major fp32
    const float* b_mlp   = (const float*)d_in[6];   // (256,)
    float* out = (float*)d_out;                      // (32,128,64,256) fp32

    // workspace layout (fp32): att[2048] | proj_c[2048*256] | proj_e[128*256]
    float* att    = (float*)d_ws;
    float* proj_c = att + BS1 * NEC;
    float* proj_e = proj_c + BS1 * NEC * MD;

    prep_kernel<<<272 + BS1, 256, 0, stream>>>(crit, ehr, w_mlp, w_align,
                                               proj_c, proj_e, att);
    final_kernel<<<BS1 * BS2, 256, 0, stream>>>(att, proj_c, proj_e, b_mlp, out);
}

// Round 4
// 311.653 us; speedup vs baseline: 1.2071x; 1.2071x over previous
//
#include <hip/hip_runtime.h>

// Problem constants
#define BS1 32
#define BS2 128
#define NEC 64
#define QD  256   // Q_DIM
#define MD  256   // MLP_DIM (== MEM_DIM)

// Fused prep kernel, 256 threads/block:
//   blocks [0,256):   proj_c rows 8*blk      = crit rows @ W_mlp[:256,:]
//   blocks [256,272): proj_e rows 8*(blk-256) = ehr rows @ W_mlp[256:,:]
//   blocks [272,304): att[b,:] = softmax_e(crit[b,e,:] . W_align[:256]), b = blk-272
//                     (logit_e[p] and b_align are constant over axis e -> cancel)
__global__ __launch_bounds__(256)
void prep_kernel(const float* __restrict__ crit,
                 const float* __restrict__ ehr,
                 const float* __restrict__ w_mlp,
                 const float* __restrict__ w_align,
                 float* __restrict__ proj_c,
                 float* __restrict__ proj_e,
                 float* __restrict__ att) {
    __shared__ float smem[8 * QD];     // GEMM A-tile (8 KB) or wa[256]
    __shared__ float logits[NEC];
    int tid = threadIdx.x;
    int blk = blockIdx.x;

    if (blk < 272) {
        // ---- 8-row GEMM: out[m0:m0+8, :] = A[m0:m0+8, :] @ B ----
        const float* A; const float* B; float* out; int m0;
        if (blk < 256) { A = crit; B = w_mlp;           out = proj_c; m0 = blk * 8; }
        else           { A = ehr;  B = w_mlp + QD * MD; out = proj_e; m0 = (blk - 256) * 8; }
        {
            const float* src = A + m0 * QD + tid * 8;
            float4 a0 = *(const float4*)src;
            float4 a1 = *(const float4*)(src + 4);
            *(float4*)&smem[tid * 8]     = a0;
            *(float4*)&smem[tid * 8 + 4] = a1;
        }
        __syncthreads();
        int r = tid >> 5;            // row in [0,8)
        int c = (tid & 31) * 8;      // col base
        float acc[8] = {0.f,0.f,0.f,0.f,0.f,0.f,0.f,0.f};
        #pragma unroll 4
        for (int k = 0; k < QD; ++k) {
            float a = smem[r * QD + k];
            const float* bp = B + k * MD + c;
            float4 b0 = *(const float4*)bp;
            float4 b1 = *(const float4*)(bp + 4);
            acc[0] = fmaf(a, b0.x, acc[0]);
            acc[1] = fmaf(a, b0.y, acc[1]);
            acc[2] = fmaf(a, b0.z, acc[2]);
            acc[3] = fmaf(a, b0.w, acc[3]);
            acc[4] = fmaf(a, b1.x, acc[4]);
            acc[5] = fmaf(a, b1.y, acc[5]);
            acc[6] = fmaf(a, b1.z, acc[6]);
            acc[7] = fmaf(a, b1.w, acc[7]);
        }
        float* o = out + (m0 + r) * MD + c;
        *(float4*)o       = make_float4(acc[0], acc[1], acc[2], acc[3]);
        *(float4*)(o + 4) = make_float4(acc[4], acc[5], acc[6], acc[7]);
    } else {
        // ---- att for one b: 4 lanes per e-row ----
        int b = blk - 272;
        smem[tid] = w_align[tid];            // wa[0:256]
        __syncthreads();
        int e = tid >> 2, q = tid & 3;
        const float* row = crit + (b * NEC + e) * QD + q * 64;
        const float* w   = &smem[q * 64];
        float acc = 0.f;
        #pragma unroll
        for (int k = 0; k < 64; k += 4) {
            float4 u = *(const float4*)(row + k);
            acc = fmaf(u.x, w[k + 0], acc);
            acc = fmaf(u.y, w[k + 1], acc);
            acc = fmaf(u.z, w[k + 2], acc);
            acc = fmaf(u.w, w[k + 3], acc);
        }
        // sum the 4-lane group (lanes q^1, q^2 within the wave)
        acc += __shfl_xor(acc, 1);
        acc += __shfl_xor(acc, 2);
        if (q == 0) logits[e] = acc;
        __syncthreads();
        if (tid < NEC) {                     // wave 0 does the 64-wide softmax
            float l = logits[tid];
            float m = l;
            #pragma unroll
            for (int off = 32; off; off >>= 1) m = fmaxf(m, __shfl_xor(m, off));
            float ex = __expf(l - m);
            float s = ex;
            #pragma unroll
            for (int off = 32; off; off >>= 1) s += __shfl_xor(s, off);
            att[b * NEC + tid] = ex / s;
        }
    }
}

// h[b,p,e,d] = att[b,e] * (proj_c[b,e,d] + proj_e[p,d]) + b_mlp[d]
// One block per (b,p). LDS-free: pe/bm/att are loop-invariant per thread,
// held in registers; proj_c read from L2; plain float4 stores (NT stores
// regressed 27 us in R2 -- the L2 write-back path already hits HBM ceiling).
__global__ __launch_bounds__(256)
void final_kernel(const float* __restrict__ att,
                  const float* __restrict__ proj_c,
                  const float* __restrict__ proj_e,
                  const float* __restrict__ b_mlp,
                  float*       __restrict__ out) {
    int tid = threadIdx.x;
    int bp  = blockIdx.x;
    int b = bp >> 7, p = bp & 127;
    int wid = tid >> 5;                 // [0,8)
    int d   = (tid & 31) * 8;           // [0,256) step 8

    const float4 e0 = *(const float4*)(proj_e + p * MD + d);
    const float4 e1 = *(const float4*)(proj_e + p * MD + d + 4);
    const float4 m0 = *(const float4*)(b_mlp + d);
    const float4 m1 = *(const float4*)(b_mlp + d + 4);

    const float* attp = att + b * NEC + wid;
    float a[8];
    #pragma unroll
    for (int pass = 0; pass < 8; ++pass) a[pass] = attp[pass * 8];

    // e = pass*8 + wid; idx = pass*256 + tid; out offset = idx*8 (wave-contiguous 2 KiB)
    const float* pc = proj_c + (b * NEC + wid) * MD + d;
    float*       o  = out + (size_t)bp * (NEC * MD) + tid * 8;

    #pragma unroll
    for (int pass = 0; pass < 8; ++pass) {
        float4 c0 = *(const float4*)pc;
        float4 c1 = *(const float4*)(pc + 4);
        float4 r0, r1;
        r0.x = fmaf(a[pass], c0.x + e0.x, m0.x);
        r0.y = fmaf(a[pass], c0.y + e0.y, m0.y);
        r0.z = fmaf(a[pass], c0.z + e0.z, m0.z);
        r0.w = fmaf(a[pass], c0.w + e0.w, m0.w);
        r1.x = fmaf(a[pass], c1.x + e1.x, m1.x);
        r1.y = fmaf(a[pass], c1.y + e1.y, m1.y);
        r1.z = fmaf(a[pass], c1.z + e1.z, m1.z);
        r1.w = fmaf(a[pass], c1.w + e1.w, m1.w);
        *(float4*)o       = r0;
        *(float4*)(o + 4) = r1;
        pc += 8 * MD;      // e advances by 8 per pass
        o  += 256 * 8;     // idx advances by 256 threads * 8 floats
    }
}

extern "C" void kernel_launch(void* const* d_in, const int* in_sizes, int n_in,
                              void* d_out, int out_size, void* d_ws, size_t ws_size,
                              hipStream_t stream) {
    // setup_inputs order: ehr_vector, criteria, ec_mask, W_align, b_align, W_mlp, b_mlp
    const float* ehr     = (const float*)d_in[0];   // (128, 256) fp32
    const float* crit    = (const float*)d_in[1];   // (32, 64, 256) fp32
    // d_in[2] ec_mask: all-ones, unused by reference
    const float* w_align = (const float*)d_in[3];   // (512,) -> use [:256]
    // d_in[4] b_align: cancels in softmax
    const float* w_mlp   = (const float*)d_in[5];   // (512, 256) row-major fp32
    const float* b_mlp   = (const float*)d_in[6];   // (256,)
    float* out = (float*)d_out;                      // (32,128,64,256) fp32

    // workspace layout (fp32): att[2048] | proj_c[2048*256] | proj_e[128*256]
    float* att    = (float*)d_ws;
    float* proj_c = att + BS1 * NEC;
    float* proj_e = proj_c + BS1 * NEC * MD;

    prep_kernel<<<272 + BS1, 256, 0, stream>>>(crit, ehr, w_mlp, w_align,
                                               proj_c, proj_e, att);
    final_kernel<<<BS1 * BS2, 256, 0, stream>>>(att, proj_c, proj_e, b_mlp, out);
}

// Round 5
// 308.817 us; speedup vs baseline: 1.2182x; 1.0092x over previous
//
#include <hip/hip_runtime.h>

// Problem constants
#define BS1 32
#define BS2 128
#define NEC 64
#define QD  256   // Q_DIM
#define MD  256   // MLP_DIM (== MEM_DIM)

// Fused prep kernel, 256 threads/block:
//   blocks [0,256):   proj_c rows 8*blk      = crit rows @ W_mlp[:256,:]
//   blocks [256,272): proj_e rows 8*(blk-256) = ehr rows @ W_mlp[256:,:]
//   blocks [272,304): att[b,:] = softmax_e(crit[b,e,:] . W_align[:256]), b = blk-272
//                     (logit_e[p] and b_align are constant over axis e -> cancel)
__global__ __launch_bounds__(256)
void prep_kernel(const float* __restrict__ crit,
                 const float* __restrict__ ehr,
                 const float* __restrict__ w_mlp,
                 const float* __restrict__ w_align,
                 float* __restrict__ proj_c,
                 float* __restrict__ proj_e,
                 float* __restrict__ att) {
    __shared__ float smem[8 * QD];     // GEMM A-tile (8 KB) or wa[256]
    __shared__ float logits[NEC];
    int tid = threadIdx.x;
    int blk = blockIdx.x;

    if (blk < 272) {
        // ---- 8-row GEMM: out[m0:m0+8, :] = A[m0:m0+8, :] @ B ----
        const float* A; const float* B; float* out; int m0;
        if (blk < 256) { A = crit; B = w_mlp;           out = proj_c; m0 = blk * 8; }
        else           { A = ehr;  B = w_mlp + QD * MD; out = proj_e; m0 = (blk - 256) * 8; }
        {
            const float* src = A + m0 * QD + tid * 8;
            float4 a0 = *(const float4*)src;
            float4 a1 = *(const float4*)(src + 4);
            *(float4*)&smem[tid * 8]     = a0;
            *(float4*)&smem[tid * 8 + 4] = a1;
        }
        __syncthreads();
        int r = tid >> 5;            // row in [0,8)
        int c = (tid & 31) * 8;      // col base
        float acc[8] = {0.f,0.f,0.f,0.f,0.f,0.f,0.f,0.f};
        #pragma unroll 4
        for (int k = 0; k < QD; ++k) {
            float a = smem[r * QD + k];
            const float* bp = B + k * MD + c;
            float4 b0 = *(const float4*)bp;
            float4 b1 = *(const float4*)(bp + 4);
            acc[0] = fmaf(a, b0.x, acc[0]);
            acc[1] = fmaf(a, b0.y, acc[1]);
            acc[2] = fmaf(a, b0.z, acc[2]);
            acc[3] = fmaf(a, b0.w, acc[3]);
            acc[4] = fmaf(a, b1.x, acc[4]);
            acc[5] = fmaf(a, b1.y, acc[5]);
            acc[6] = fmaf(a, b1.z, acc[6]);
            acc[7] = fmaf(a, b1.w, acc[7]);
        }
        float* o = out + (m0 + r) * MD + c;
        *(float4*)o       = make_float4(acc[0], acc[1], acc[2], acc[3]);
        *(float4*)(o + 4) = make_float4(acc[4], acc[5], acc[6], acc[7]);
    } else {
        // ---- att for one b: 4 lanes per e-row ----
        int b = blk - 272;
        smem[tid] = w_align[tid];            // wa[0:256]
        __syncthreads();
        int e = tid >> 2, q = tid & 3;
        const float* row = crit + (b * NEC + e) * QD + q * 64;
        const float* w   = &smem[q * 64];
        float acc = 0.f;
        #pragma unroll
        for (int k = 0; k < 64; k += 4) {
            float4 u = *(const float4*)(row + k);
            acc = fmaf(u.x, w[k + 0], acc);
            acc = fmaf(u.y, w[k + 1], acc);
            acc = fmaf(u.z, w[k + 2], acc);
            acc = fmaf(u.w, w[k + 3], acc);
        }
        // sum the 4-lane group (lanes q^1, q^2 within the wave)
        acc += __shfl_xor(acc, 1);
        acc += __shfl_xor(acc, 2);
        if (q == 0) logits[e] = acc;
        __syncthreads();
        if (tid < NEC) {                     // wave 0 does the 64-wide softmax
            float l = logits[tid];
            float m = l;
            #pragma unroll
            for (int off = 32; off; off >>= 1) m = fmaxf(m, __shfl_xor(m, off));
            float ex = __expf(l - m);
            float s = ex;
            #pragma unroll
            for (int off = 32; off; off >>= 1) s += __shfl_xor(s, off);
            att[b * NEC + tid] = ex / s;
        }
    }
}

// h[b,p,e,d] = att[b,e] * (proj_c[b,e,d] + proj_e[p,d]) + b_mlp[d]
// One block per (b,p). Fill-pattern memory ops: every wave instruction
// (load pc / store out) touches a contiguous 1 KiB span (16 B/lane at
// 16 B lane stride), matching the 6.4 TB/s poison-fill store pattern.
// 16 passes; e = pass*4 + wid, d = (tid&63)*4.
__global__ __launch_bounds__(256)
void final_kernel(const float* __restrict__ att,
                  const float* __restrict__ proj_c,
                  const float* __restrict__ proj_e,
                  const float* __restrict__ b_mlp,
                  float*       __restrict__ out) {
    int tid = threadIdx.x;
    int bp  = blockIdx.x;
    int b = bp >> 7, p = bp & 127;
    int wid = tid >> 6;                 // wave id [0,4)
    int d   = (tid & 63) * 4;           // [0,256) step 4

    const float4 pe = *(const float4*)(proj_e + p * MD + d);
    const float4 bm = *(const float4*)(b_mlp + d);

    // att[b, pass*4 + wid]: wave-uniform scalars, loop-invariant
    const float* attp = att + b * NEC + wid;
    float a[16];
    #pragma unroll
    for (int pass = 0; pass < 16; ++pass) a[pass] = attp[pass * 4];

    const float* pc = proj_c + (b * NEC + wid) * MD + d;   // row e = wid
    float*       o  = out + (size_t)bp * (NEC * MD) + tid * 4;

    #pragma unroll
    for (int pass = 0; pass < 16; ++pass) {
        float4 c0 = *(const float4*)pc;
        float4 r0;
        r0.x = fmaf(a[pass], c0.x + pe.x, bm.x);
        r0.y = fmaf(a[pass], c0.y + pe.y, bm.y);
        r0.z = fmaf(a[pass], c0.z + pe.z, bm.z);
        r0.w = fmaf(a[pass], c0.w + pe.w, bm.w);
        *(float4*)o = r0;
        pc += 4 * MD;      // e advances by 4 per pass
        o  += 1024;        // 256 threads * 4 floats
    }
}

extern "C" void kernel_launch(void* const* d_in, const int* in_sizes, int n_in,
                              void* d_out, int out_size, void* d_ws, size_t ws_size,
                              hipStream_t stream) {
    // setup_inputs order: ehr_vector, criteria, ec_mask, W_align, b_align, W_mlp, b_mlp
    const float* ehr     = (const float*)d_in[0];   // (128, 256) fp32
    const float* crit    = (const float*)d_in[1];   // (32, 64, 256) fp32
    // d_in[2] ec_mask: all-ones, unused by reference
    const float* w_align = (const float*)d_in[3];   // (512,) -> use [:256]
    // d_in[4] b_align: cancels in softmax
    const float* w_mlp   = (const float*)d_in[5];   // (512, 256) row-major fp32
    const float* b_mlp   = (const float*)d_in[6];   // (256,)
    float* out = (float*)d_out;                      // (32,128,64,256) fp32

    // workspace layout (fp32): att[2048] | proj_c[2048*256] | proj_e[128*256]
    float* att    = (float*)d_ws;
    float* proj_c = att + BS1 * NEC;
    float* proj_e = proj_c + BS1 * NEC * MD;

    prep_kernel<<<272 + BS1, 256, 0, stream>>>(crit, ehr, w_mlp, w_align,
                                               proj_c, proj_e, att);
    final_kernel<<<BS1 * BS2, 256, 0, stream>>>(att, proj_c, proj_e, b_mlp, out);
}